// Round 1
// baseline (1411.356 us; speedup 1.0000x reference)
//
#include <hip/hip_runtime.h>

#define NNODE 16384
#define IN_F  256
#define OUT_F 128
#define ROWS  8      // rows per block
#define MAXNB 256    // neighbor-list capacity per row (mean ~33, P(>256) ~ 0)

// One block handles ROWS consecutive rows of A.
// Phase A: coalesced float4 scan of A rows -> compact nonzero col indices to LDS.
// Phase B: gather-sum H rows (thread t = feature t), divide by deg+1.
// Phase C: multiply [ROWS x 256] aggregate by W^T (W is [128 x 256] row-major),
//          split the 256-long dot across two half-groups, LDS reduce.
__global__ __launch_bounds__(256, 8) void gcn_fused_kernel(
    const float* __restrict__ A,
    const float* __restrict__ H,
    const float* __restrict__ W,
    float* __restrict__ out)
{
    __shared__ int   s_cnt[ROWS];
    __shared__ int   s_idx[ROWS][MAXNB];
    __shared__ float s_agg[ROWS][IN_F];
    __shared__ float s_part[OUT_F][ROWS];

    const int t = threadIdx.x;
    const int row0 = blockIdx.x * ROWS;

    if (t < ROWS) s_cnt[t] = 0;
    __syncthreads();

    // ---- Phase A: scan A rows, build neighbor lists ----
    for (int r = 0; r < ROWS; ++r) {
        const float4* A4 = reinterpret_cast<const float4*>(
            A + (size_t)(row0 + r) * NNODE);
        #pragma unroll
        for (int k = 0; k < NNODE / (256 * 4); ++k) {   // 16 iterations
            float4 v = A4[k * 256 + t];
            int j = (k * 256 + t) * 4;
            if (v.x != 0.f) { int p = atomicAdd(&s_cnt[r], 1); if (p < MAXNB) s_idx[r][p] = j;     }
            if (v.y != 0.f) { int p = atomicAdd(&s_cnt[r], 1); if (p < MAXNB) s_idx[r][p] = j + 1; }
            if (v.z != 0.f) { int p = atomicAdd(&s_cnt[r], 1); if (p < MAXNB) s_idx[r][p] = j + 2; }
            if (v.w != 0.f) { int p = atomicAdd(&s_cnt[r], 1); if (p < MAXNB) s_idx[r][p] = j + 3; }
        }
    }
    __syncthreads();

    // ---- Phase B: gather-sum H rows; thread t owns feature c = t ----
    for (int r = 0; r < ROWS; ++r) {
        const int cnt = s_cnt[r];
        float acc = 0.f;
        for (int k = 0; k < cnt; ++k) {
            const int j = s_idx[r][k];               // LDS broadcast
            acc += H[(size_t)j * IN_F + t];          // coalesced 1KB row read
        }
        s_agg[r][t] = acc / (float)(cnt + 1);
    }
    __syncthreads();

    // ---- Phase C: out[row, o] = dot(agg[row,:], W[o,:]) ----
    const int o    = t & (OUT_F - 1);
    const int half = t >> 7;                         // 0 or 1
    float acc[ROWS];
    #pragma unroll
    for (int r = 0; r < ROWS; ++r) acc[r] = 0.f;

    const float* Wrow = W + (size_t)o * IN_F + half * (IN_F / 2);
    for (int k = 0; k < IN_F / 2; ++k) {
        const float wv = Wrow[k];
        const int c = half * (IN_F / 2) + k;
        #pragma unroll
        for (int r = 0; r < ROWS; ++r) acc[r] += wv * s_agg[r][c];
    }

    if (half == 1) {
        #pragma unroll
        for (int r = 0; r < ROWS; ++r) s_part[o][r] = acc[r];
    }
    __syncthreads();
    if (half == 0) {
        #pragma unroll
        for (int r = 0; r < ROWS; ++r)
            out[(size_t)(row0 + r) * OUT_F + o] = acc[r] + s_part[o][r];
    }
}

extern "C" void kernel_launch(void* const* d_in, const int* in_sizes, int n_in,
                              void* d_out, int out_size, void* d_ws, size_t ws_size,
                              hipStream_t stream) {
    const float* A = (const float*)d_in[0];   // [N, N]
    const float* H = (const float*)d_in[1];   // [N, IN_F]
    const float* W = (const float*)d_in[2];   // [OUT_F, IN_F]
    float* out = (float*)d_out;               // [N, OUT_F]

    dim3 grid(NNODE / ROWS);                  // 2048 blocks
    dim3 block(256);
    gcn_fused_kernel<<<grid, block, 0, stream>>>(A, H, W, out);
}